// Round 1
// 831.278 us; speedup vs baseline: 1.1754x; 1.1754x over previous
//
#include <hip/hip_runtime.h>
#include <stdint.h>

// B=2, T=2048, D=3584, N=16, KH=8, H=256, G=2, WINDOW=1024
// Inputs FLOAT32; compute bf16 MFMA; output FLOAT32.
// attn_mask unused: tril ∧ triu(1-W) ≡ t-1023 <= s <= t (diag always valid).

typedef short bf16x8 __attribute__((ext_vector_type(8)));   // 8 bf16 = 4 VGPRs
typedef float f32x4 __attribute__((ext_vector_type(4)));

#define MFMA16(a, b, c) __builtin_amdgcn_mfma_f32_16x16x32_bf16((a), (b), (c), 0, 0, 0)

__device__ __forceinline__ uint16_t f2bf(float f) {
  uint32_t u = __builtin_bit_cast(uint32_t, f);
  u += 0x7FFFu + ((u >> 16) & 1u);   // RNE
  return (uint16_t)(u >> 16);
}
__device__ __forceinline__ float bf2f(uint16_t u) {
  return __builtin_bit_cast(float, (uint32_t)u << 16);
}
// async global->LDS, 16B/lane; LDS dest must be wave-uniform base + lane*16.
__device__ __forceinline__ void async16(void* lds, const void* g) {
  __builtin_amdgcn_global_load_lds(
      (const __attribute__((address_space(1))) uint32_t*)g,
      (__attribute__((address_space(3))) uint32_t*)lds, 16, 0, 0);
}

// ---------------------------------------------------------------------------
// x f32 -> bf16 (row-major copy); 8 elems/thread
// ---------------------------------------------------------------------------
__global__ void convert_x(const float* __restrict__ x, uint16_t* __restrict__ xb) {
  size_t i = ((size_t)blockIdx.x * 256 + threadIdx.x) * 8;
  f32x4 a = *(const f32x4*)(x + i);
  f32x4 b = *(const f32x4*)(x + i + 4);
  bf16x8 r;
  r[0] = (short)f2bf(a[0]); r[1] = (short)f2bf(a[1]);
  r[2] = (short)f2bf(a[2]); r[3] = (short)f2bf(a[3]);
  r[4] = (short)f2bf(b[0]); r[5] = (short)f2bf(b[1]);
  r[6] = (short)f2bf(b[2]); r[7] = (short)f2bf(b[3]);
  *(bf16x8*)(xb + i) = r;
}

// ---------------------------------------------------------------------------
// Weight transposes (f32 in, bf16 out), B^T (n-major, k-contiguous) layout
// ---------------------------------------------------------------------------
__global__ void transpose_qkvw(const float* __restrict__ qw,
                               const float* __restrict__ kvw,
                               uint16_t* __restrict__ WqkvT) {
  __shared__ uint16_t tile[64][65];
  const int j0 = blockIdx.x * 64;
  const int d0 = blockIdx.y * 64;
  const int t = threadIdx.x;
  const int jl = t & 63;
  const int q4 = t >> 6;
  const int j = j0 + jl;
  const float* src;
  if (j0 < 4096) {
    src = qw + (size_t)(j >> 8) * 3584 * 256 + (j & 255);
  } else {
    int j2 = j - 4096;
    src = kvw + ((size_t)((j2 >> 11) * 8 + ((j2 >> 8) & 7)) * 3584) * 256 + (j2 & 255);
  }
#pragma unroll
  for (int r = 0; r < 16; ++r) {
    int dl = r * 4 + q4;
    tile[jl][dl] = f2bf(src[(size_t)(d0 + dl) * 256]);
  }
  __syncthreads();
#pragma unroll
  for (int r = 0; r < 16; ++r) {
    int jl2 = r * 4 + q4;
    WqkvT[(size_t)(j0 + jl2) * 3584 + d0 + jl] = tile[jl2][jl];
  }
}

// WoT[d][j] = o_w flat (4096 x 3584)[j][d], f32 -> bf16
__global__ void transpose_ow(const float* __restrict__ ow, uint16_t* __restrict__ WoT) {
  __shared__ uint16_t tile[64][65];
  const int d0 = blockIdx.x * 64;
  const int j0 = blockIdx.y * 64;
  const int t = threadIdx.x;
  const int c = t & 63;
  const int q4 = t >> 6;
#pragma unroll
  for (int r = 0; r < 16; ++r) {
    int jl = r * 4 + q4;
    tile[c][jl] = f2bf(ow[(size_t)(j0 + jl) * 3584 + d0 + c]);   // coalesced in d
  }
  __syncthreads();
#pragma unroll
  for (int r = 0; r < 16; ++r) {
    int dl = r * 4 + q4;
    WoT[(size_t)(d0 + dl) * 4096 + j0 + c] = tile[dl][c];        // coalesced in j
  }
}

// ---------------------------------------------------------------------------
// GEMM, 256x256-tile deep-pipelined schedule (8-phase-template family):
//   C[M,Nc] = A[M,Kd] * B, Bt = B^T (Nc x Kd), all bf16.
//   512 threads = 8 waves (2 M x 4 N); per-wave output 128x64 (acc[8][4]).
//   BK=32; LDS = 4-slot ring x (A 16KB + B 16KB) = 128 KB.
//   Staging: global_load_lds width-16, linear LDS dest + inverse-swizzled
//   global source (chunk ^= (row>>1)&3); ds_read applies same XOR -> the
//   16-row fragment read spreads over all bank groups (2-way, free).
//   Per K-tile: 2 phases (m-half quadrants, 16 MFMA each), raw s_barrier,
//   setprio(1) around MFMA, ONE counted s_waitcnt vmcnt(8) (2 tiles in
//   flight, never drained to 0 in the loop).
//   Safety: tile t's slot ((t)&3) is rewritten only at iter t+1 phase 0,
//   which is after iter t's trailing barrier (all reads retired). Tile t+1's
//   loads are drained by iter t's vmcnt(8) + barrier before iter t+1 reads.
// EPI 0: epilogue routes cols to Q / K / V^T bf16 buffers.
// EPI 1: epilogue stores f32 to Oq.
// ---------------------------------------------------------------------------
template <int EPI>
__global__ __launch_bounds__(512, 2) void gemm256(
    const uint16_t* __restrict__ A, const uint16_t* __restrict__ Bt,
    int Kd, int Nc, int nbx,
    void* __restrict__ Oqv, uint16_t* __restrict__ Ok, uint16_t* __restrict__ Ov) {
  __shared__ uint16_t lds[4 * 16384];   // 128 KiB

  const int tid = threadIdx.x;
  const int lane = tid & 63;
  const int quad = lane >> 4;
  const int l15 = lane & 15;
  const int wave = tid >> 6;
  const int wm = wave & 1;        // M half (128 rows)
  const int wn = wave >> 1;       // N quarter (64 cols)

  // T1: XCD-aware bijective swizzle (requires nwg % 8 == 0; 512 and 224 both ok)
  const int nwg = gridDim.x;
  const int chunk = nwg >> 3;
  const int wg = blockIdx.x;
  const int swz = (wg & 7) * chunk + (wg >> 3);
  const int by = swz / nbx;
  const int bx = swz - by * nbx;
  const int m0 = by * 256;
  const int n0 = bx * 256;

  f32x4 acc[8][4];
#pragma unroll
  for (int i = 0; i < 8; ++i)
#pragma unroll
    for (int j = 0; j < 4; ++j) acc[i][j] = f32x4{0.f, 0.f, 0.f, 0.f};

  // Staging source pointers (pre-swizzled global chunk; LDS dest stays linear)
  const int srow = tid >> 2;              // 0..127
  const int sck = tid & 3;                // 16B chunk within 64B row
  const int gck0 = sck ^ ((srow >> 1) & 3);          // rows 0..127 and 128..255
  const int gck1 = sck ^ (((srow + 128) >> 1) & 3);  // share (row>>1)&3 parity
  const uint16_t* gA0 = A + (size_t)(m0 + srow) * Kd + gck0 * 8;
  const uint16_t* gA1 = A + (size_t)(m0 + srow + 128) * Kd + gck1 * 8;
  const uint16_t* gB0 = Bt + (size_t)(n0 + srow) * Kd + gck0 * 8;
  const uint16_t* gB1 = Bt + (size_t)(n0 + srow + 128) * Kd + gck1 * 8;

  const int T = Kd >> 5;                  // K tiles (112 or 128, both >= 3)

  // Prologue: stage tiles 0,1,2 into slots 0,1,2 (12 loads/thread)
#pragma unroll
  for (int pt = 0; pt < 3; ++pt) {
    uint16_t* sd = lds + pt * 16384;
    const int kt = pt * 32;
    async16(sd + tid * 8, gA0 + kt);
    async16(sd + 4096 + tid * 8, gA1 + kt);
    async16(sd + 8192 + tid * 8, gB0 + kt);
    async16(sd + 12288 + tid * 8, gB1 + kt);
  }
  asm volatile("s_waitcnt vmcnt(8)" ::: "memory");   // tile 0 landed
  __builtin_amdgcn_s_barrier();

  const int arow = wm * 128;
  const int brow = wn * 64;

  for (int t = 0; t < T; ++t) {
    const uint16_t* sA = lds + (t & 3) * 16384;
    const uint16_t* sB = sA + 8192;
    uint16_t* sd = lds + ((t + 3) & 3) * 16384;      // prefetch dest slot
    int ts = t + 3;
    if (ts >= T) ts = T - 1;                         // clamped source; never consumed
    const int ktS = ts * 32;

    // ---- phase 0: B frags (all 4) + A frags m-half 0; stage next A ----
    bf16x8 bfr[4], af[4];
#pragma unroll
    for (int fn = 0; fn < 4; ++fn) {
      const int r = brow + fn * 16 + l15;
      bfr[fn] = *(const bf16x8*)(sB + r * 32 + ((quad ^ ((r >> 1) & 3)) << 3));
    }
#pragma unroll
    for (int i = 0; i < 4; ++i) {
      const int r = arow + i * 16 + l15;
      af[i] = *(const bf16x8*)(sA + r * 32 + ((quad ^ ((r >> 1) & 3)) << 3));
    }
    async16(sd + tid * 8, gA0 + ktS);
    async16(sd + 4096 + tid * 8, gA1 + ktS);
    __builtin_amdgcn_s_barrier();
    __builtin_amdgcn_s_setprio(1);
#pragma unroll
    for (int i = 0; i < 4; ++i)
#pragma unroll
      for (int fn = 0; fn < 4; ++fn)
        acc[i][fn] = MFMA16(af[i], bfr[fn], acc[i][fn]);
    __builtin_amdgcn_s_setprio(0);
    __builtin_amdgcn_s_barrier();

    // ---- phase 1: A frags m-half 1 (B reused); stage next B; counted vmcnt ----
#pragma unroll
    for (int i = 0; i < 4; ++i) {
      const int r = arow + 64 + i * 16 + l15;
      af[i] = *(const bf16x8*)(sA + r * 32 + ((quad ^ ((r >> 1) & 3)) << 3));
    }
    async16(sd + 8192 + tid * 8, gB0 + ktS);
    async16(sd + 12288 + tid * 8, gB1 + ktS);
    asm volatile("s_waitcnt vmcnt(8)" ::: "memory");  // drains tile t+1; t+2/t+3 stay in flight
    __builtin_amdgcn_s_barrier();
    __builtin_amdgcn_s_setprio(1);
#pragma unroll
    for (int i = 0; i < 4; ++i)
#pragma unroll
      for (int fn = 0; fn < 4; ++fn)
        acc[4 + i][fn] = MFMA16(af[i], bfr[fn], acc[4 + i][fn]);
    __builtin_amdgcn_s_setprio(0);
    __builtin_amdgcn_s_barrier();
  }

  // Drain remaining LDS-DMA before wave exit (slots die with the workgroup).
  asm volatile("s_waitcnt vmcnt(0)" ::: "memory");

  // C layout per 16x16 frag: col = lane&15, row = quad*4 + reg (guide-verified)
  const int rowb = m0 + wm * 128;
  const int colb = n0 + wn * 64;
  if (EPI == 0) {
    if (n0 < 4096) {           // Q: (B*T, N*H)
      uint16_t* Oq = (uint16_t*)Oqv;
#pragma unroll
      for (int fm = 0; fm < 8; ++fm)
#pragma unroll
        for (int fn = 0; fn < 4; ++fn) {
          const int r0 = rowb + fm * 16 + quad * 4;
          const int c = colb + fn * 16 + l15;
#pragma unroll
          for (int reg = 0; reg < 4; ++reg)
            Oq[(size_t)(r0 + reg) * 4096 + c] = f2bf(acc[fm][fn][reg]);
        }
    } else if (n0 < 6144) {    // K: (B*T, KH*H)
#pragma unroll
      for (int fm = 0; fm < 8; ++fm)
#pragma unroll
        for (int fn = 0; fn < 4; ++fn) {
          const int r0 = rowb + fm * 16 + quad * 4;
          const int c = colb + fn * 16 + l15 - 4096;
#pragma unroll
          for (int reg = 0; reg < 4; ++reg)
            Ok[(size_t)(r0 + reg) * 2048 + c] = f2bf(acc[fm][fn][reg]);
        }
    } else {                   // V transposed: Vt[b][kvh][h][t]
#pragma unroll
      for (int fm = 0; fm < 8; ++fm)
#pragma unroll
        for (int fn = 0; fn < 4; ++fn) {
          const int r0 = rowb + fm * 16 + quad * 4;   // 4 consecutive t
          const int c2 = colb + fn * 16 + l15 - 6144;
          const int kvh = c2 >> 8, h = c2 & 255;
          const int bb = r0 >> 11, tt = r0 & 2047;
          ushort4 pk;
          pk.x = f2bf(acc[fm][fn][0]);
          pk.y = f2bf(acc[fm][fn][1]);
          pk.z = f2bf(acc[fm][fn][2]);
          pk.w = f2bf(acc[fm][fn][3]);
          *(ushort4*)(Ov + ((((size_t)bb * 8 + kvh) * 256 + h) * 2048 + tt)) = pk;
        }
    }
  } else {                     // f32 output
    float* Oq = (float*)Oqv;
#pragma unroll
    for (int fm = 0; fm < 8; ++fm)
#pragma unroll
      for (int fn = 0; fn < 4; ++fn) {
        const int r0 = rowb + fm * 16 + quad * 4;
        const int c = colb + fn * 16 + l15;
#pragma unroll
        for (int reg = 0; reg < 4; ++reg)
          Oq[(size_t)(r0 + reg) * Nc + c] = acc[fm][fn][reg];
      }
  }
}

// ---------------------------------------------------------------------------
// RoPE in place on Q (B,T,N,H) and K (B,T,KH,H) [bf16]; Q additionally * 0.0625
// ---------------------------------------------------------------------------
__global__ void rope_kernel(uint16_t* __restrict__ Qb, uint16_t* __restrict__ Kb,
                            const int* __restrict__ segpos) {
  const size_t QN = (size_t)2 * 2048 * 16 * 128;   // 8388608 Q pairs
  size_t idx = (size_t)blockIdx.x * 256 + threadIdx.x;
  uint16_t* buf;
  size_t base;
  int i, t, b;
  bool isQ = idx < QN;
  if (isQ) {
    i = (int)(idx & 127);
    int nn = (int)((idx >> 7) & 15);
    t = (int)((idx >> 11) & 2047);
    b = (int)(idx >> 22);
    base = ((size_t)((b * 2048 + t) * 16 + nn) << 8) + i;
    buf = Qb;
  } else {
    size_t x2 = idx - QN;
    i = (int)(x2 & 127);
    int kh = (int)((x2 >> 7) & 7);
    t = (int)((x2 >> 10) & 2047);
    b = (int)(x2 >> 21);
    base = ((size_t)((b * 2048 + t) * 8 + kh) << 8) + i;
    buf = Kb;
  }
  float pos = (float)segpos[b * 2048 + t];
  float inv = exp2f((float)i * (-13.287712379549449f / 128.f));  // 10000^(-i/128)
  float ang = pos * inv;
  float sn = sinf(ang), cs = cosf(ang);
  float x1 = bf2f(buf[base]);
  float x2v = bf2f(buf[base + 128]);
  float o1 = x1 * cs - x2v * sn;
  float o2 = x2v * cs + x1 * sn;
  if (isQ) { o1 *= 0.0625f; o2 *= 0.0625f; }
  buf[base] = f2bf(o1);
  buf[base + 128] = f2bf(o2);
}

// ---------------------------------------------------------------------------
// Flash attention, softcap + sliding window (identical to passing version).
// ---------------------------------------------------------------------------
__global__ __launch_bounds__(256) void attn_kernel(
    const uint16_t* __restrict__ Qb, const uint16_t* __restrict__ Kb,
    const uint16_t* __restrict__ Vt, uint16_t* __restrict__ enc) {
  __shared__ uint16_t KV[256 * 72];     // K phase: [s<64][264]; V phase: [h<256][72]
  __shared__ uint16_t Ps[4 * 32 * 72];  // per-wave P (32 x 64, stride 72)
  const int tid = threadIdx.x;
  const int lane = tid & 63;
  const int wave = tid >> 6;
  const int quad = lane >> 4;
  const int l15 = lane & 15;
  const int qt0 = blockIdx.x * 64;
  const int b = blockIdx.y >> 3;
  const int kvh = blockIdx.y & 7;
  const int g = wave & 1;
  const int wr = (wave >> 1) * 32;
  const int n = kvh * 2 + g;

  f32x4 oacc[2][16];
#pragma unroll
  for (int mt = 0; mt < 2; ++mt)
#pragma unroll
    for (int ht = 0; ht < 16; ++ht) oacc[mt][ht] = f32x4{0.f, 0.f, 0.f, 0.f};
  float mrow[2][4], lrow[2][4];
#pragma unroll
  for (int mt = 0; mt < 2; ++mt)
#pragma unroll
    for (int r = 0; r < 4; ++r) { mrow[mt][r] = -50.f; lrow[mt][r] = 0.f; }

  const uint16_t* qp0 =
      Qb + ((size_t)((b * 2048 + qt0 + wr + l15) * 16 + n) << 8) + quad * 8;
  const uint16_t* qp1 = qp0 + (size_t)16 * 4096;

  const int krow = tid >> 5;
  const int kcol = (tid & 31) * 8;
  const uint16_t* kg = Kb + ((size_t)((b * 2048 + krow) * 8 + kvh) << 8) + kcol;
  const int vrow = tid >> 3;
  const int vcol = (tid & 7) * 8;
  const uint16_t* vg = Vt + (((size_t)(b * 8 + kvh) * 256 + vrow) << 11) + vcol;

  int lo = qt0 - 1023;
  if (lo < 0) lo = 0;
  const int s0_start = (lo >> 6) << 6;

  for (int s0 = s0_start; s0 <= qt0; s0 += 64) {
    bf16x8 kr[8], vr[8];
#pragma unroll
    for (int r = 0; r < 8; ++r) {
      kr[r] = *(const bf16x8*)(kg + (size_t)(s0 + r * 8) * 2048);
      vr[r] = *(const bf16x8*)(vg + s0 + (size_t)(r * 32) * 2048);
    }
    __syncthreads();   // [A] prior tile's V reads complete
#pragma unroll
    for (int r = 0; r < 8; ++r)
      *(bf16x8*)(KV + (r * 8 + krow) * 264 + kcol) = kr[r];
    __syncthreads();   // [B] K visible

    f32x4 sac[2][4];
#pragma unroll
    for (int mt = 0; mt < 2; ++mt)
#pragma unroll
      for (int j = 0; j < 4; ++j) sac[mt][j] = f32x4{0.f, 0.f, 0.f, 0.f};
#pragma unroll
    for (int c = 0; c < 8; ++c) {
      bf16x8 q0 = *(const bf16x8*)(qp0 + c * 32);
      bf16x8 q1 = *(const bf16x8*)(qp1 + c * 32);
#pragma unroll
      for (int j = 0; j < 4; ++j) {
        bf16x8 kf = *(const bf16x8*)(KV + (j * 16 + l15) * 264 + (c * 4 + quad) * 8);
        sac[0][j] = MFMA16(q0, kf, sac[0][j]);
        sac[1][j] = MFMA16(q1, kf, sac[1][j]);
      }
    }

#pragma unroll
    for (int mt = 0; mt < 2; ++mt) {
      const int tbase = qt0 + wr + mt * 16 + quad * 4;
#pragma unroll
      for (int reg = 0; reg < 4; ++reg) {
        const int t = tbase + reg;
        float pv[4];
        float mx = -1e30f;
#pragma unroll
        for (int j = 0; j < 4; ++j) {
          int s = s0 + j * 16 + l15;
          float v = sac[mt][j][reg];
          float e = __expf(v * 0.04f);                 // e^{2v/50}
          float scv = 50.f - 100.f / (e + 1.f);        // 50*tanh(v/50)
          bool valid = (s <= t) && (s + 1024 > t);
          v = valid ? scv : -1e30f;
          pv[j] = v;
          mx = fmaxf(mx, v);
        }
        mx = fmaxf(mx, __shfl_xor(mx, 1));
        mx = fmaxf(mx, __shfl_xor(mx, 2));
        mx = fmaxf(mx, __shfl_xor(mx, 4));
        mx = fmaxf(mx, __shfl_xor(mx, 8));
        float mold = mrow[mt][reg];
        float mnew = fmaxf(mold, mx);
        mrow[mt][reg] = mnew;
        float alpha = __expf(mold - mnew);
        float rs = 0.f;
#pragma unroll
        for (int j = 0; j < 4; ++j) {
          float p = __expf(pv[j] - mnew);
          pv[j] = p;
          rs += p;
        }
        rs += __shfl_xor(rs, 1);
        rs += __shfl_xor(rs, 2);
        rs += __shfl_xor(rs, 4);
        rs += __shfl_xor(rs, 8);
        lrow[mt][reg] = lrow[mt][reg] * alpha + rs;
#pragma unroll
        for (int ht = 0; ht < 16; ++ht) oacc[mt][ht][reg] *= alpha;
        const int r = mt * 16 + quad * 4 + reg;
#pragma unroll
        for (int j = 0; j < 4; ++j)
          Ps[wave * 2304 + r * 72 + j * 16 + l15] = f2bf(pv[j]);
      }
    }
    __syncthreads();   // [C] all waves' K reads done
#pragma unroll
    for (int r = 0; r < 8; ++r)
      *(bf16x8*)(KV + (r * 32 + vrow) * 72 + vcol) = vr[r];
    __syncthreads();   // [D] V visible

#pragma unroll
    for (int c2 = 0; c2 < 2; ++c2) {
      const int lch = c2 * 4 + quad;
      bf16x8 pf0 = *(const bf16x8*)(Ps + wave * 2304 + l15 * 72 + lch * 8);
      bf16x8 pf1 = *(const bf16x8*)(Ps + wave * 2304 + (16 + l15) * 72 + lch * 8);
#pragma unroll
      for (int ht = 0; ht < 16; ++ht) {
        bf16x8 vf = *(const bf16x8*)(KV + (ht * 16 + l15) * 72 + lch * 8);
        oacc[0][ht] = MFMA16(pf0, vf, oacc[0][ht]);
        oacc[1][ht] = MFMA16(pf1, vf, oacc[1][ht]);
      }
    }
  }

#pragma unroll
  for (int mt = 0; mt < 2; ++mt) {
    const int tb = qt0 + wr + mt * 16 + quad * 4;
#pragma unroll
    for (int reg = 0; reg < 4; ++reg) {
      float li = 1.f / lrow[mt][reg];
      size_t base = ((size_t)((b * 2048 + tb + reg) * 16 + n) << 8) + l15;
#pragma unroll
      for (int ht = 0; ht < 16; ++ht)
        enc[base + ht * 16] = f2bf(oacc[mt][ht][reg] * li);
    }
  }
}

// ---------------------------------------------------------------------------
extern "C" void kernel_launch(void* const* d_in, const int* in_sizes, int n_in,
                              void* d_out, int out_size, void* d_ws, size_t ws_size,
                              hipStream_t stream) {
  const float* x = (const float*)d_in[0];
  const int* segpos = (const int*)d_in[1];
  // d_in[2] = attn_mask — implied by window; unused
  const float* qw = (const float*)d_in[3];
  const float* kvw = (const float*)d_in[4];
  const float* ow = (const float*)d_in[5];
  float* out = (float*)d_out;

  uint16_t* ws = (uint16_t*)d_ws;
  uint16_t* WqkvT = ws;                              // 29,360,128 elems
  uint16_t* enc = ws;                                // aliases WqkvT (dead after gemm<0>)
  uint16_t* xb = ws + (size_t)29360128;              // 14,680,064 (aliases WoT; dead after gemm<0>)
  uint16_t* WoT = ws + (size_t)29360128;             // 14,680,064 (written after attn)
  uint16_t* Qb = ws + (size_t)44040192;              // 16,777,216
  uint16_t* Kb = ws + (size_t)60817408;              // 8,388,608
  uint16_t* Vt = ws + (size_t)69206016;              // 8,388,608  (total ~155 MB)

  convert_x<<<7168, 256, 0, stream>>>(x, xb);
  transpose_qkvw<<<dim3(128, 56), 256, 0, stream>>>(qw, kvw, WqkvT);
  // 256x256 tiles: QKV = (4096 x 8192) -> 16 x 32 = 512 wgs; O = (4096 x 3584) -> 16 x 14 = 224 wgs
  gemm256<0><<<dim3(512), dim3(512), 0, stream>>>(xb, WqkvT, 3584, 8192, 32, Qb, Kb, Vt);
  rope_kernel<<<49152, 256, 0, stream>>>(Qb, Kb, segpos);
  attn_kernel<<<dim3(32, 16), 256, 0, stream>>>(Qb, Kb, Vt, enc);
  transpose_ow<<<dim3(56, 64), 256, 0, stream>>>(ow, WoT);   // xb dead; reuse region
  gemm256<1><<<dim3(224), dim3(512), 0, stream>>>(enc, WoT, 4096, 3584, 14, out, nullptr, nullptr);
}